// Round 4
// baseline (355.566 us; speedup 1.0000x reference)
//
#include <hip/hip_runtime.h>

// B=2, M=8192, H=8, D=64, hd=512, S=512, n_seg=16
// d_in: q(8388608 f32), k, v (unused), w_qkv(786432 f32), w_out(262144 f32)
// d_out: 8388608 f32

typedef short bfrag __attribute__((ext_vector_type(8)));   // 8 bf16 (4 VGPR)
typedef short bhalf4 __attribute__((ext_vector_type(4)));  // 4 bf16 (2 VGPR)
typedef float ffrag __attribute__((ext_vector_type(4)));   // MFMA C/D
typedef short svec4 __attribute__((ext_vector_type(4)));
typedef unsigned uvec2 __attribute__((ext_vector_type(2)));

__device__ inline short f2bf(float x) {  // RNE
  unsigned u = __builtin_bit_cast(unsigned, x);
  u = (u + 0x7fffu + ((u >> 16) & 1u)) >> 16;
  return (short)u;
}
// fast pack: round-half-up (bias negligible for continuous data)
__device__ inline unsigned pk2f(float a, float b) {
  unsigned ua = (__builtin_bit_cast(unsigned, a) + 0x8000u) >> 16;
  unsigned ub = __builtin_bit_cast(unsigned, b) + 0x8000u;
  return ua | (ub & 0xffff0000u);
}
__device__ inline float fexp2(float x) {
#if __has_builtin(__builtin_amdgcn_exp2f)
  return __builtin_amdgcn_exp2f(x);   // raw v_exp_f32 (hw is base-2)
#else
  return __expf(x * 0.6931471805599453f);
#endif
}

// Hilbert d->(x,y) on 128x128 (bit-identical to reference forward map).
__device__ inline int d2xy128(int d) {
  int x = 0, y = 0, t = d;
  for (int s = 1; s < 128; s <<= 1) {
    int rx = 1 & (t >> 1);
    int ry = 1 & (t ^ rx);
    if (ry == 0) {
      if (rx == 1) { x = s - 1 - x; y = s - 1 - y; }
      int tt = x; x = y; y = tt;
    }
    x += s * rx;
    y += s * ry;
    t >>= 2;
  }
  return y * 128 + x;
}

// ---------------- Kernel 1: head-mean + eff. weights + perm (closed form) ---
__global__ __launch_bounds__(256) void prep_kernel(
    const float* __restrict__ q, const float* __restrict__ w_qkv,
    const float* __restrict__ w_out, short* __restrict__ xmean,
    short* __restrict__ weff, short* __restrict__ woutb,
    int* __restrict__ perm) {
  int i = blockIdx.x * 256 + threadIdx.x;
  if (i < 1048576) {
    int bm = i >> 6, d = i & 63;
    const float* p = q + (size_t)bm * 512 + d;
    float s = 0.f;
#pragma unroll
    for (int h = 0; h < 8; ++h) s += p[h * 64];
    xmean[i] = f2bf(s * 0.125f);
  } else if (i < 1048576 + 98304) {
    int j = i - 1048576;
    int f = j >> 6;
    const float* p = w_qkv + (size_t)f * 512 + (j & 63);
    float s = 0.f;
#pragma unroll
    for (int r = 0; r < 8; ++r) s += p[r * 64];
    if (f < 512) s *= 0.125f * 1.44269504088896f;  // D^-0.5 * log2(e)
    weff[j] = f2bf(s);
  } else if (i < 1048576 + 98304 + 262144) {
    int j = i - 1048576 - 98304;
    woutb[j] = f2bf(w_out[j]);
  } else if (i < 1048576 + 98304 + 262144 + 8192) {
    int r = i - (1048576 + 98304 + 262144);
    perm[r] = d2xy128(r < 4096 ? r : r + 8192);
  }
}

// ---------------- Kernel 2: QKV projection into permuted/segment layouts ----
// Qs[b][p][f'], Ks[b][p][f'] (rows = permuted positions); Vt[b][n][h][d][t]
__global__ __launch_bounds__(256) void qkv_kernel(
    const short* __restrict__ xmean, const short* __restrict__ weff,
    const int* __restrict__ perm, short* __restrict__ Qs,
    short* __restrict__ Ks, short* __restrict__ Vt) {
  int tid = threadIdx.x;
  int w = tid >> 6, lane = tid & 63;
  int ml = lane & 15, quad = lane >> 4;
  int rg = blockIdx.x >> 3, fq = blockIdx.x & 7;
  int r0 = rg * 64 + w * 16;  // 16 permuted rows per wave
  int r = r0 + ml;
  int b = r >> 13, p = r & 8191;
  int src = (b << 13) + perm[p];
  bfrag a0 = *(const bfrag*)(xmean + (size_t)src * 64 + quad * 8);
  bfrag a1 = *(const bfrag*)(xmean + (size_t)src * 64 + 32 + quad * 8);
  int p0 = r0 & 8191;
  int bq = r0 >> 13;
  int nseg = p0 >> 9;
  int sbase = (p0 & 511) + quad * 4;

  auto loadW = [&](bfrag (&wf)[2], int nt) {
    const short* wp = weff + (size_t)(nt * 16 + ml) * 64 + quad * 8;
    wf[0] = *(const bfrag*)(wp);
    wf[1] = *(const bfrag*)(wp + 32);
  };
  auto emit = [&](bfrag (&wf)[2], int nt) {
    int f0 = nt * 16;
    ffrag acc = {0.f, 0.f, 0.f, 0.f};
    if (f0 < 1024) {
      // D[f][row] = W·X^T : lane holds 4 consecutive f -> svec4
      acc = __builtin_amdgcn_mfma_f32_16x16x32_bf16(wf[0], a0, acc, 0, 0, 0);
      acc = __builtin_amdgcn_mfma_f32_16x16x32_bf16(wf[1], a1, acc, 0, 0, 0);
      short* dst = (f0 < 512) ? Qs : Ks;
      svec4 pk;
#pragma unroll
      for (int g = 0; g < 4; ++g) pk[g] = f2bf(acc[g]);
      *(svec4*)(dst + (size_t)(r0 + ml) * 512 + (f0 & 511) + quad * 4) = pk;
    } else {
      // D[row][f] = X·W^T : lane holds 4 consecutive t -> svec4 into Vt
      acc = __builtin_amdgcn_mfma_f32_16x16x32_bf16(a0, wf[0], acc, 0, 0, 0);
      acc = __builtin_amdgcn_mfma_f32_16x16x32_bf16(a1, wf[1], acc, 0, 0, 0);
      int fl = f0 + ml - 1024;
      int hh = fl >> 6, dd = fl & 63;
      svec4 pk;
#pragma unroll
      for (int g = 0; g < 4; ++g) pk[g] = f2bf(acc[g]);
      *(svec4*)(Vt + ((((size_t)bq * 16 + nseg) * 8 + hh) * 64 + dd) * 512 +
                sbase) = pk;
    }
  };

  int base = fq * 12;
  bfrag wA[2], wB[2];
  loadW(wA, base);
#pragma unroll 1
  for (int it = 0; it < 6; ++it) {
    int nt0 = base + it * 2;
    loadW(wB, nt0 + 1);
    emit(wA, nt0);
    loadW(wA, (it < 5) ? nt0 + 2 : base);
    emit(wB, nt0 + 1);
  }
}

// ---------------- Kernel 3: segment attention, no-max softmax, S^T=K·Q^T ----
// Transpose-free: the S^T C-layout (lane q=ml, t=quad*4+g) IS the B-operand
// layout of mfma_f32_16x16x16_bf16 (k=quad*4+j). exp+pack feeds PV directly;
// zero DS-pipe traffic. K dbuf'd one tile ahead; V issued at body top.
// grid 1024 = 4 blocks/CU; bid%8==h keeps (b,n,h) L2/XCD-local.
__global__ __launch_bounds__(256, 4) void attn_kernel(
    const short* __restrict__ Qs, const short* __restrict__ Ks,
    const short* __restrict__ Vt, const int* __restrict__ perm,
    short* __restrict__ aout) {
  int tid = threadIdx.x;
  int w = tid >> 6, lane = tid & 63;
  int ml = lane & 15, quad = lane >> 4;
  int sh = blockIdx.x & 255;
  int qq = blockIdx.x >> 8;
  int b = sh >> 7;
  int n = (sh >> 3) & 15;
  int h = sh & 7;
  size_t segrow = (size_t)(b * 8192 + n * 512);
  const short* Qseg = Qs + segrow * 512 + h * 64;
  const short* Kseg = Ks + segrow * 512 + h * 64;
  const short* Vseg = Vt + (((size_t)(b * 16 + n) * 8 + h) * 64) * 512;
  int q0 = qq * 128 + w * 32;  // 32 q-cols per wave (2 n-tiles)
  bfrag qa[2][2];
#pragma unroll
  for (int nq = 0; nq < 2; ++nq)
#pragma unroll
    for (int ks = 0; ks < 2; ++ks)
      qa[nq][ks] = *(const bfrag*)(Qseg + (size_t)(q0 + nq * 16 + ml) * 512 +
                                   ks * 32 + quad * 8);
  ffrag o[2][4];
  float lrun[2] = {0.f, 0.f};
#pragma unroll
  for (int nq = 0; nq < 2; ++nq)
#pragma unroll
    for (int dt = 0; dt < 4; ++dt) o[nq][dt] = (ffrag){0.f, 0.f, 0.f, 0.f};

  auto loadK = [&](bfrag (&kk)[2][2], int t0) {
#pragma unroll
    for (int mt = 0; mt < 2; ++mt)
#pragma unroll
      for (int ks = 0; ks < 2; ++ks)
        kk[mt][ks] = *(const bfrag*)(Kseg + (size_t)(t0 + mt * 16 + ml) * 512 +
                                     ks * 32 + quad * 8);
  };
  // body for one 32-t tile: V A-frags are 8B short4 (4 consecutive t)
  auto body = [&](bfrag (&kk)[2][2], int t0) {
    bhalf4 vv[4][2];
#pragma unroll
    for (int dt = 0; dt < 4; ++dt)
#pragma unroll
      for (int hf = 0; hf < 2; ++hf)
        vv[dt][hf] = *(const bhalf4*)(Vseg + (size_t)(dt * 16 + ml) * 512 +
                                      t0 + hf * 16 + quad * 4);
#pragma unroll
    for (int nq = 0; nq < 2; ++nq) {
      ffrag c0 = {0.f, 0.f, 0.f, 0.f}, c1 = {0.f, 0.f, 0.f, 0.f};
      c0 = __builtin_amdgcn_mfma_f32_16x16x32_bf16(kk[0][0], qa[nq][0], c0, 0, 0, 0);
      c0 = __builtin_amdgcn_mfma_f32_16x16x32_bf16(kk[0][1], qa[nq][1], c0, 0, 0, 0);
      c1 = __builtin_amdgcn_mfma_f32_16x16x32_bf16(kk[1][0], qa[nq][0], c1, 0, 0, 0);
      c1 = __builtin_amdgcn_mfma_f32_16x16x32_bf16(kk[1][1], qa[nq][1], c1, 0, 0, 0);
      // P^T = 2^(S^T); lane holds q=ml, t = quad*4+g (c0), 16+quad*4+g (c1)
      float e0 = fexp2(c0[0]), e1 = fexp2(c0[1]);
      float e2 = fexp2(c0[2]), e3 = fexp2(c0[3]);
      float e4 = fexp2(c1[0]), e5 = fexp2(c1[1]);
      float e6 = fexp2(c1[2]), e7 = fexp2(c1[3]);
      lrun[nq] += ((e0 + e1) + (e2 + e3)) + ((e4 + e5) + (e6 + e7));
      uvec2 u0, u1;
      u0[0] = pk2f(e0, e1); u0[1] = pk2f(e2, e3);
      u1[0] = pk2f(e4, e5); u1[1] = pk2f(e6, e7);
      bhalf4 pb0 = __builtin_bit_cast(bhalf4, u0);  // B-frag t in [t0,t0+16)
      bhalf4 pb1 = __builtin_bit_cast(bhalf4, u1);  // B-frag t in [t0+16,+32)
      // O^T[d][q] += V^T · P^T via two K=16 MFMAs per dt
#pragma unroll
      for (int dt = 0; dt < 4; ++dt) {
        o[nq][dt] = __builtin_amdgcn_mfma_f32_16x16x16bf16_1k(
            vv[dt][0], pb0, o[nq][dt], 0, 0, 0);
        o[nq][dt] = __builtin_amdgcn_mfma_f32_16x16x16bf16_1k(
            vv[dt][1], pb1, o[nq][dt], 0, 0, 0);
      }
    }
  };

  bfrag kA[2][2], kB[2][2];
  loadK(kA, 0);
#pragma unroll 1
  for (int jj = 0; jj < 8; ++jj) {
    loadK(kB, jj * 64 + 32);
    body(kA, jj * 64);
    loadK(kA, (jj * 64 + 64) & 511);  // wraps on last iter (unused)
    body(kB, jj * 64 + 32);
  }
  // epilogue: reduce l across quads, normalize, perm-scatter
#pragma unroll
  for (int nq = 0; nq < 2; ++nq) {
    float l = lrun[nq];
    l += __shfl_xor(l, 16);
    l += __shfl_xor(l, 32);
    float inv = 1.f / l;
    int sout = q0 + nq * 16 + ml;
    int om = perm[n * 512 + sout];
    size_t base = ((size_t)(b * 8192 + om)) * 512 + h * 64;
#pragma unroll
    for (int dt = 0; dt < 4; ++dt) {
      svec4 pk;
#pragma unroll
      for (int g = 0; g < 4; ++g) pk[g] = f2bf(o[nq][dt][g] * inv);
      *(svec4*)(aout + base + dt * 16 + quad * 4) = pk;
    }
  }
}

// ---------------- Kernel 4: output projection (16384x512 @ 512x512^T) ------
// 64-row tiles, grid 1024 (4 blocks/CU). D[c][r] -> float4 stores; dbuf.
__global__ __launch_bounds__(256, 4) void proj_kernel(
    const short* __restrict__ aout, const short* __restrict__ woutb,
    float* __restrict__ out) {
  int tid = threadIdx.x;
  int w = tid >> 6, lane = tid & 63;
  int ml = lane & 15, quad = lane >> 4;
  int rb = blockIdx.x >> 2;
  int cb = blockIdx.x & 3;
  int r0 = rb * 64 + w * 16;
  int c0 = cb * 128;
  ffrag acc[8];
#pragma unroll
  for (int nt = 0; nt < 8; ++nt) acc[nt] = (ffrag){0.f, 0.f, 0.f, 0.f};

  auto loadA = [&](bfrag& af, int k0) {
    af = *(const bfrag*)(aout + (size_t)(r0 + ml) * 512 + k0 + quad * 8);
  };
  auto loadB = [&](bfrag (&bf)[8], int k0) {
#pragma unroll
    for (int nt = 0; nt < 8; ++nt)
      bf[nt] = *(const bfrag*)(woutb + (size_t)(c0 + nt * 16 + ml) * 512 + k0 +
                               quad * 8);
  };
  auto accum = [&](bfrag& af, bfrag (&bf)[8]) {
#pragma unroll
    for (int nt = 0; nt < 8; ++nt)
      acc[nt] = __builtin_amdgcn_mfma_f32_16x16x32_bf16(bf[nt], af, acc[nt], 0, 0, 0);
  };

  bfrag aA, aB, bA[8], bB[8];
  loadA(aA, 0);
  loadB(bA, 0);
#pragma unroll 1
  for (int it = 0; it < 8; ++it) {
    int k1 = it * 64 + 32;
    loadA(aB, k1);
    loadB(bB, k1);
    accum(aA, bA);
    int k2 = (it < 7) ? it * 64 + 64 : 0;
    loadA(aA, k2);
    loadB(bA, k2);
    accum(aB, bB);
  }
#pragma unroll
  for (int nt = 0; nt < 8; ++nt)
    *(ffrag*)(out + (size_t)(r0 + ml) * 512 + c0 + nt * 16 + quad * 4) =
        acc[nt];
}

extern "C" void kernel_launch(void* const* d_in, const int* in_sizes, int n_in,
                              void* d_out, int out_size, void* d_ws,
                              size_t ws_size, hipStream_t stream) {
  const float* q = (const float*)d_in[0];
  const float* w_qkv = (const float*)d_in[3];
  const float* w_out = (const float*)d_in[4];
  float* out = (float*)d_out;

  char* ws = (char*)d_ws;
  int* perm = (int*)ws;                       //     32768 B
  short* xmean = (short*)(ws + 32768);        //   2097152 B
  short* weff = (short*)(ws + 2129920);       //    196608 B
  short* woutb = (short*)(ws + 2326528);      //    524288 B
  short* Qs = (short*)(ws + 2850816);         //  16777216 B
  short* Ks = (short*)(ws + 19628032);        //  16777216 B
  short* Vt = (short*)(ws + 36405248);        //  16777216 B
  short* aout = (short*)(ws + 53182464);      //  16777216 B  (total ~70 MB)

  prep_kernel<<<5536, 256, 0, stream>>>(q, w_qkv, w_out, xmean, weff, woutb,
                                        perm);
  qkv_kernel<<<2048, 256, 0, stream>>>(xmean, weff, perm, Qs, Ks, Vt);
  attn_kernel<<<1024, 256, 0, stream>>>(Qs, Ks, Vt, perm, aout);
  proj_kernel<<<1024, 256, 0, stream>>>(aout, woutb, out);
}

// Round 5
// 321.342 us; speedup vs baseline: 1.1065x; 1.1065x over previous
//
#include <hip/hip_runtime.h>

// B=2, M=8192, H=8, D=64, hd=512, S=512, n_seg=16
// d_in: q(8388608 f32), k, v (unused), w_qkv(786432 f32), w_out(262144 f32)
// d_out: 8388608 f32

typedef short bfrag __attribute__((ext_vector_type(8)));   // 8 bf16 (4 VGPR)
typedef short bhalf4 __attribute__((ext_vector_type(4)));  // 4 bf16 (2 VGPR)
typedef float ffrag __attribute__((ext_vector_type(4)));   // MFMA C/D
typedef short svec4 __attribute__((ext_vector_type(4)));
typedef unsigned uvec2 __attribute__((ext_vector_type(2)));

__device__ inline short f2bf(float x) {  // RNE
  unsigned u = __builtin_bit_cast(unsigned, x);
  u = (u + 0x7fffu + ((u >> 16) & 1u)) >> 16;
  return (short)u;
}
// fast pack: round-half-up (bias negligible for continuous data)
__device__ inline unsigned pk2f(float a, float b) {
  unsigned ua = (__builtin_bit_cast(unsigned, a) + 0x8000u) >> 16;
  unsigned ub = __builtin_bit_cast(unsigned, b) + 0x8000u;
  return ua | (ub & 0xffff0000u);
}
__device__ inline float fexp2(float x) {
#if __has_builtin(__builtin_amdgcn_exp2f)
  return __builtin_amdgcn_exp2f(x);   // raw v_exp_f32 (hw is base-2)
#else
  return __expf(x * 0.6931471805599453f);
#endif
}

// Hilbert d->(x,y) on 128x128 (bit-identical to reference forward map).
__device__ inline int d2xy128(int d) {
  int x = 0, y = 0, t = d;
  for (int s = 1; s < 128; s <<= 1) {
    int rx = 1 & (t >> 1);
    int ry = 1 & (t ^ rx);
    if (ry == 0) {
      if (rx == 1) { x = s - 1 - x; y = s - 1 - y; }
      int tt = x; x = y; y = tt;
    }
    x += s * rx;
    y += s * ry;
    t >>= 2;
  }
  return y * 128 + x;
}

// ---------------- Kernel 1: head-mean + eff. weights + perm (closed form) ---
__global__ __launch_bounds__(256) void prep_kernel(
    const float* __restrict__ q, const float* __restrict__ w_qkv,
    const float* __restrict__ w_out, short* __restrict__ xmean,
    short* __restrict__ weff, short* __restrict__ woutb,
    int* __restrict__ perm) {
  int i = blockIdx.x * 256 + threadIdx.x;
  if (i < 1048576) {
    int bm = i >> 6, d = i & 63;
    const float* p = q + (size_t)bm * 512 + d;
    float s = 0.f;
#pragma unroll
    for (int h = 0; h < 8; ++h) s += p[h * 64];
    xmean[i] = f2bf(s * 0.125f);
  } else if (i < 1048576 + 98304) {
    int j = i - 1048576;
    int f = j >> 6;
    const float* p = w_qkv + (size_t)f * 512 + (j & 63);
    float s = 0.f;
#pragma unroll
    for (int r = 0; r < 8; ++r) s += p[r * 64];
    if (f < 512) s *= 0.125f * 1.44269504088896f;  // D^-0.5 * log2(e)
    weff[j] = f2bf(s);
  } else if (i < 1048576 + 98304 + 262144) {
    int j = i - 1048576 - 98304;
    woutb[j] = f2bf(w_out[j]);
  } else if (i < 1048576 + 98304 + 262144 + 8192) {
    int r = i - (1048576 + 98304 + 262144);
    perm[r] = d2xy128(r < 4096 ? r : r + 8192);
  }
}

// ---------------- Kernel 2: QKV projection into permuted/segment layouts ----
// Qs[b][p][f'], Ks[b][p][f'] (rows = permuted positions); Vt[b][n][h][d][t]
__global__ __launch_bounds__(256) void qkv_kernel(
    const short* __restrict__ xmean, const short* __restrict__ weff,
    const int* __restrict__ perm, short* __restrict__ Qs,
    short* __restrict__ Ks, short* __restrict__ Vt) {
  int tid = threadIdx.x;
  int w = tid >> 6, lane = tid & 63;
  int ml = lane & 15, quad = lane >> 4;
  int rg = blockIdx.x >> 3, fq = blockIdx.x & 7;
  int r0 = rg * 64 + w * 16;  // 16 permuted rows per wave
  int r = r0 + ml;
  int b = r >> 13, p = r & 8191;
  int src = (b << 13) + perm[p];
  bfrag a0 = *(const bfrag*)(xmean + (size_t)src * 64 + quad * 8);
  bfrag a1 = *(const bfrag*)(xmean + (size_t)src * 64 + 32 + quad * 8);
  int p0 = r0 & 8191;
  int bq = r0 >> 13;
  int nseg = p0 >> 9;
  int sbase = (p0 & 511) + quad * 4;

  auto loadW = [&](bfrag (&wf)[2], int nt) {
    const short* wp = weff + (size_t)(nt * 16 + ml) * 64 + quad * 8;
    wf[0] = *(const bfrag*)(wp);
    wf[1] = *(const bfrag*)(wp + 32);
  };
  auto emit = [&](bfrag (&wf)[2], int nt) {
    int f0 = nt * 16;
    ffrag acc = {0.f, 0.f, 0.f, 0.f};
    if (f0 < 1024) {
      // D[f][row] = W·X^T : lane holds 4 consecutive f -> svec4
      acc = __builtin_amdgcn_mfma_f32_16x16x32_bf16(wf[0], a0, acc, 0, 0, 0);
      acc = __builtin_amdgcn_mfma_f32_16x16x32_bf16(wf[1], a1, acc, 0, 0, 0);
      short* dst = (f0 < 512) ? Qs : Ks;
      svec4 pk;
#pragma unroll
      for (int g = 0; g < 4; ++g) pk[g] = f2bf(acc[g]);
      *(svec4*)(dst + (size_t)(r0 + ml) * 512 + (f0 & 511) + quad * 4) = pk;
    } else {
      // D[row][f] = X·W^T : lane holds 4 consecutive t -> svec4 into Vt
      acc = __builtin_amdgcn_mfma_f32_16x16x32_bf16(a0, wf[0], acc, 0, 0, 0);
      acc = __builtin_amdgcn_mfma_f32_16x16x32_bf16(a1, wf[1], acc, 0, 0, 0);
      int fl = f0 + ml - 1024;
      int hh = fl >> 6, dd = fl & 63;
      svec4 pk;
#pragma unroll
      for (int g = 0; g < 4; ++g) pk[g] = f2bf(acc[g]);
      *(svec4*)(Vt + ((((size_t)bq * 16 + nseg) * 8 + hh) * 64 + dd) * 512 +
                sbase) = pk;
    }
  };

  int base = fq * 12;
  bfrag wA[2], wB[2];
  loadW(wA, base);
#pragma unroll 1
  for (int it = 0; it < 6; ++it) {
    int nt0 = base + it * 2;
    loadW(wB, nt0 + 1);
    emit(wA, nt0);
    loadW(wA, (it < 5) ? nt0 + 2 : base);
    emit(wB, nt0 + 1);
  }
}

// ---------------- Kernel 3: segment attention, no-max softmax, S^T=K·Q^T ----
// Transpose-free: the S^T C-layout (lane q=ml, t=quad*4+g) IS the B-operand
// layout of mfma_f32_16x16x16_bf16 (k=quad*4+j). exp+pack feeds PV directly;
// zero DS-pipe traffic. K AND V double-buffered one tile ahead.
// launch_bounds (256,2): do NOT force 4 waves/EU — that 128-unified-reg
// budget spilled to scratch in R4 (WRITE_SIZE 16->169 MB). ~124 regs here
// gives 4 waves/SIMD naturally.
__global__ __launch_bounds__(256, 2) void attn_kernel(
    const short* __restrict__ Qs, const short* __restrict__ Ks,
    const short* __restrict__ Vt, const int* __restrict__ perm,
    short* __restrict__ aout) {
  int tid = threadIdx.x;
  int w = tid >> 6, lane = tid & 63;
  int ml = lane & 15, quad = lane >> 4;
  int sh = blockIdx.x & 255;
  int qq = blockIdx.x >> 8;
  int b = sh >> 7;
  int n = (sh >> 3) & 15;
  int h = sh & 7;
  size_t segrow = (size_t)(b * 8192 + n * 512);
  const short* Qseg = Qs + segrow * 512 + h * 64;
  const short* Kseg = Ks + segrow * 512 + h * 64;
  const short* Vseg = Vt + (((size_t)(b * 16 + n) * 8 + h) * 64) * 512;
  int q0 = qq * 128 + w * 32;  // 32 q-cols per wave (2 n-tiles)
  bfrag qa[2][2];
#pragma unroll
  for (int nq = 0; nq < 2; ++nq)
#pragma unroll
    for (int ks = 0; ks < 2; ++ks)
      qa[nq][ks] = *(const bfrag*)(Qseg + (size_t)(q0 + nq * 16 + ml) * 512 +
                                   ks * 32 + quad * 8);
  ffrag o[2][4];
  float lrun[2] = {0.f, 0.f};
#pragma unroll
  for (int nq = 0; nq < 2; ++nq)
#pragma unroll
    for (int dt = 0; dt < 4; ++dt) o[nq][dt] = (ffrag){0.f, 0.f, 0.f, 0.f};

  auto loadK = [&](bfrag (&kk)[2][2], int t0) {
#pragma unroll
    for (int mt = 0; mt < 2; ++mt)
#pragma unroll
      for (int ks = 0; ks < 2; ++ks)
        kk[mt][ks] = *(const bfrag*)(Kseg + (size_t)(t0 + mt * 16 + ml) * 512 +
                                     ks * 32 + quad * 8);
  };
  auto loadV = [&](bhalf4 (&vv)[4][2], int t0) {
#pragma unroll
    for (int dt = 0; dt < 4; ++dt)
#pragma unroll
      for (int hf = 0; hf < 2; ++hf)
        vv[dt][hf] = *(const bhalf4*)(Vseg + (size_t)(dt * 16 + ml) * 512 +
                                      t0 + hf * 16 + quad * 4);
  };
  auto body = [&](bfrag (&kk)[2][2], bhalf4 (&vv)[4][2]) {
#pragma unroll
    for (int nq = 0; nq < 2; ++nq) {
      ffrag c0 = {0.f, 0.f, 0.f, 0.f}, c1 = {0.f, 0.f, 0.f, 0.f};
      c0 = __builtin_amdgcn_mfma_f32_16x16x32_bf16(kk[0][0], qa[nq][0], c0, 0, 0, 0);
      c0 = __builtin_amdgcn_mfma_f32_16x16x32_bf16(kk[0][1], qa[nq][1], c0, 0, 0, 0);
      c1 = __builtin_amdgcn_mfma_f32_16x16x32_bf16(kk[1][0], qa[nq][0], c1, 0, 0, 0);
      c1 = __builtin_amdgcn_mfma_f32_16x16x32_bf16(kk[1][1], qa[nq][1], c1, 0, 0, 0);
      // P^T = 2^(S^T); lane holds q=ml, t = quad*4+g (c0), 16+quad*4+g (c1)
      float e0 = fexp2(c0[0]), e1 = fexp2(c0[1]);
      float e2 = fexp2(c0[2]), e3 = fexp2(c0[3]);
      float e4 = fexp2(c1[0]), e5 = fexp2(c1[1]);
      float e6 = fexp2(c1[2]), e7 = fexp2(c1[3]);
      lrun[nq] += ((e0 + e1) + (e2 + e3)) + ((e4 + e5) + (e6 + e7));
      uvec2 u0, u1;
      u0[0] = pk2f(e0, e1); u0[1] = pk2f(e2, e3);
      u1[0] = pk2f(e4, e5); u1[1] = pk2f(e6, e7);
      bhalf4 pb0 = __builtin_bit_cast(bhalf4, u0);  // B-frag t in [t0,t0+16)
      bhalf4 pb1 = __builtin_bit_cast(bhalf4, u1);  // B-frag t in [t0+16,+32)
      // O^T[d][q] += V^T · P^T via two K=16 MFMAs per dt
#pragma unroll
      for (int dt = 0; dt < 4; ++dt) {
        o[nq][dt] = __builtin_amdgcn_mfma_f32_16x16x16bf16_1k(
            vv[dt][0], pb0, o[nq][dt], 0, 0, 0);
        o[nq][dt] = __builtin_amdgcn_mfma_f32_16x16x16bf16_1k(
            vv[dt][1], pb1, o[nq][dt], 0, 0, 0);
      }
    }
  };

  bfrag kA[2][2], kB[2][2];
  bhalf4 vA[4][2], vB[4][2];
  loadK(kA, 0);
  loadV(vA, 0);
#pragma unroll 1
  for (int jj = 0; jj < 8; ++jj) {
    int t1 = jj * 64 + 32;
    loadK(kB, t1);
    loadV(vB, t1);
    body(kA, vA);
    int t2 = (jj * 64 + 64) & 511;  // wraps on last iter (unused)
    loadK(kA, t2);
    loadV(vA, t2);
    body(kB, vB);
  }
  // epilogue: reduce l across quads, normalize, perm-scatter
#pragma unroll
  for (int nq = 0; nq < 2; ++nq) {
    float l = lrun[nq];
    l += __shfl_xor(l, 16);
    l += __shfl_xor(l, 32);
    float inv = 1.f / l;
    int sout = q0 + nq * 16 + ml;
    int om = perm[n * 512 + sout];
    size_t base = ((size_t)(b * 8192 + om)) * 512 + h * 64;
#pragma unroll
    for (int dt = 0; dt < 4; ++dt) {
      svec4 pk;
#pragma unroll
      for (int g = 0; g < 4; ++g) pk[g] = f2bf(o[nq][dt][g] * inv);
      *(svec4*)(aout + base + dt * 16 + quad * 4) = pk;
    }
  }
}

// ---------------- Kernel 4: output projection (16384x512 @ 512x512^T) ------
// 64-row tiles, grid 1024. D[c][r] -> float4 stores; dbuf. (256,2): don't
// force higher occupancy — register budget needs ~150 regs (R4 spill lesson).
__global__ __launch_bounds__(256, 2) void proj_kernel(
    const short* __restrict__ aout, const short* __restrict__ woutb,
    float* __restrict__ out) {
  int tid = threadIdx.x;
  int w = tid >> 6, lane = tid & 63;
  int ml = lane & 15, quad = lane >> 4;
  int rb = blockIdx.x >> 2;
  int cb = blockIdx.x & 3;
  int r0 = rb * 64 + w * 16;
  int c0 = cb * 128;
  ffrag acc[8];
#pragma unroll
  for (int nt = 0; nt < 8; ++nt) acc[nt] = (ffrag){0.f, 0.f, 0.f, 0.f};

  auto loadA = [&](bfrag& af, int k0) {
    af = *(const bfrag*)(aout + (size_t)(r0 + ml) * 512 + k0 + quad * 8);
  };
  auto loadB = [&](bfrag (&bf)[8], int k0) {
#pragma unroll
    for (int nt = 0; nt < 8; ++nt)
      bf[nt] = *(const bfrag*)(woutb + (size_t)(c0 + nt * 16 + ml) * 512 + k0 +
                               quad * 8);
  };
  auto accum = [&](bfrag& af, bfrag (&bf)[8]) {
#pragma unroll
    for (int nt = 0; nt < 8; ++nt)
      acc[nt] = __builtin_amdgcn_mfma_f32_16x16x32_bf16(bf[nt], af, acc[nt], 0, 0, 0);
  };

  bfrag aA, aB, bA[8], bB[8];
  loadA(aA, 0);
  loadB(bA, 0);
#pragma unroll 1
  for (int it = 0; it < 8; ++it) {
    int k1 = it * 64 + 32;
    loadA(aB, k1);
    loadB(bB, k1);
    accum(aA, bA);
    int k2 = (it < 7) ? it * 64 + 64 : 0;
    loadA(aA, k2);
    loadB(bA, k2);
    accum(aB, bB);
  }
#pragma unroll
  for (int nt = 0; nt < 8; ++nt)
    *(ffrag*)(out + (size_t)(r0 + ml) * 512 + c0 + nt * 16 + quad * 4) =
        acc[nt];
}

extern "C" void kernel_launch(void* const* d_in, const int* in_sizes, int n_in,
                              void* d_out, int out_size, void* d_ws,
                              size_t ws_size, hipStream_t stream) {
  const float* q = (const float*)d_in[0];
  const float* w_qkv = (const float*)d_in[3];
  const float* w_out = (const float*)d_in[4];
  float* out = (float*)d_out;

  char* ws = (char*)d_ws;
  int* perm = (int*)ws;                       //     32768 B
  short* xmean = (short*)(ws + 32768);        //   2097152 B
  short* weff = (short*)(ws + 2129920);       //    196608 B
  short* woutb = (short*)(ws + 2326528);      //    524288 B
  short* Qs = (short*)(ws + 2850816);         //  16777216 B
  short* Ks = (short*)(ws + 19628032);        //  16777216 B
  short* Vt = (short*)(ws + 36405248);        //  16777216 B
  short* aout = (short*)(ws + 53182464);      //  16777216 B  (total ~70 MB)

  prep_kernel<<<5536, 256, 0, stream>>>(q, w_qkv, w_out, xmean, weff, woutb,
                                        perm);
  qkv_kernel<<<2048, 256, 0, stream>>>(xmean, weff, perm, Qs, Ks, Vt);
  attn_kernel<<<1024, 256, 0, stream>>>(Qs, Ks, Vt, perm, aout);
  proj_kernel<<<1024, 256, 0, stream>>>(aout, woutb, out);
}

// Round 6
// 247.782 us; speedup vs baseline: 1.4350x; 1.2969x over previous
//
#include <hip/hip_runtime.h>

// B=2, M=8192, H=8, D=64, hd=512, S=512, n_seg=16
// d_in: q(8388608 f32), k, v (unused), w_qkv(786432 f32), w_out(262144 f32)
// d_out: 8388608 f32

typedef short bfrag __attribute__((ext_vector_type(8)));   // 8 bf16 (4 VGPR)
typedef short bhalf4 __attribute__((ext_vector_type(4)));  // 4 bf16 (2 VGPR)
typedef float ffrag __attribute__((ext_vector_type(4)));   // MFMA C/D
typedef short svec4 __attribute__((ext_vector_type(4)));
typedef unsigned uvec2 __attribute__((ext_vector_type(2)));

__device__ inline short f2bf(float x) {  // RNE
  unsigned u = __builtin_bit_cast(unsigned, x);
  u = (u + 0x7fffu + ((u >> 16) & 1u)) >> 16;
  return (short)u;
}
// fast pack: round-half-up (bias negligible for continuous data)
__device__ inline unsigned pk2f(float a, float b) {
  unsigned ua = (__builtin_bit_cast(unsigned, a) + 0x8000u) >> 16;
  unsigned ub = __builtin_bit_cast(unsigned, b) + 0x8000u;
  return ua | (ub & 0xffff0000u);
}
__device__ inline float fexp2(float x) {
#if __has_builtin(__builtin_amdgcn_exp2f)
  return __builtin_amdgcn_exp2f(x);   // raw v_exp_f32 (hw is base-2)
#else
  return __expf(x * 0.6931471805599453f);
#endif
}

// Hilbert d->(x,y) on 128x128 (bit-identical to reference forward map).
__device__ inline int d2xy128(int d) {
  int x = 0, y = 0, t = d;
  for (int s = 1; s < 128; s <<= 1) {
    int rx = 1 & (t >> 1);
    int ry = 1 & (t ^ rx);
    if (ry == 0) {
      if (rx == 1) { x = s - 1 - x; y = s - 1 - y; }
      int tt = x; x = y; y = tt;
    }
    x += s * rx;
    y += s * ry;
    t >>= 2;
  }
  return y * 128 + x;
}

// ---------------- Kernel 1: head-mean + eff. weights + perm (closed form) ---
__global__ __launch_bounds__(256) void prep_kernel(
    const float* __restrict__ q, const float* __restrict__ w_qkv,
    const float* __restrict__ w_out, short* __restrict__ xmean,
    short* __restrict__ weff, short* __restrict__ woutb,
    int* __restrict__ perm) {
  int i = blockIdx.x * 256 + threadIdx.x;
  if (i < 1048576) {
    int bm = i >> 6, d = i & 63;
    const float* p = q + (size_t)bm * 512 + d;
    float s = 0.f;
#pragma unroll
    for (int h = 0; h < 8; ++h) s += p[h * 64];
    xmean[i] = f2bf(s * 0.125f);
  } else if (i < 1048576 + 98304) {
    int j = i - 1048576;
    int f = j >> 6;
    const float* p = w_qkv + (size_t)f * 512 + (j & 63);
    float s = 0.f;
#pragma unroll
    for (int r = 0; r < 8; ++r) s += p[r * 64];
    if (f < 512) s *= 0.125f * 1.44269504088896f;  // D^-0.5 * log2(e)
    weff[j] = f2bf(s);
  } else if (i < 1048576 + 98304 + 262144) {
    int j = i - 1048576 - 98304;
    woutb[j] = f2bf(w_out[j]);
  } else if (i < 1048576 + 98304 + 262144 + 8192) {
    int r = i - (1048576 + 98304 + 262144);
    perm[r] = d2xy128(r < 4096 ? r : r + 8192);
  }
}

// ---------------- Kernel 2: QKV projection into permuted/segment layouts ----
// Qs[b][p][f'], Ks[b][p][f'] (rows = permuted positions); Vt[b][n][h][d][t]
// (exact copy of the 237-us build: grid 1024, f-quarter split, W dbuf)
__global__ __launch_bounds__(256) void qkv_kernel(
    const short* __restrict__ xmean, const short* __restrict__ weff,
    const int* __restrict__ perm, short* __restrict__ Qs,
    short* __restrict__ Ks, short* __restrict__ Vt) {
  int tid = threadIdx.x;
  int w = tid >> 6, lane = tid & 63;
  int ml = lane & 15, quad = lane >> 4;
  int rg = blockIdx.x >> 2, fq = blockIdx.x & 3;
  int r0 = rg * 64 + w * 16;  // 16 permuted rows per wave
  int r = r0 + ml;
  int b = r >> 13, p = r & 8191;
  int src = (b << 13) + perm[p];
  bfrag a0 = *(const bfrag*)(xmean + (size_t)src * 64 + quad * 8);
  bfrag a1 = *(const bfrag*)(xmean + (size_t)src * 64 + 32 + quad * 8);
  int p0 = r0 & 8191;
  int bq = r0 >> 13;
  int nseg = p0 >> 9;
  int sbase = (p0 & 511) + quad * 4;

  auto loadW = [&](bfrag (&wf)[2], int nt) {
    const short* wp = weff + (size_t)(nt * 16 + ml) * 64 + quad * 8;
    wf[0] = *(const bfrag*)(wp);
    wf[1] = *(const bfrag*)(wp + 32);
  };
  auto emit = [&](bfrag (&wf)[2], int nt) {
    int f0 = nt * 16;
    ffrag acc = {0.f, 0.f, 0.f, 0.f};
    if (f0 < 1024) {
      // D[f][row] = W·X^T : lane holds 4 consecutive f -> svec4
      acc = __builtin_amdgcn_mfma_f32_16x16x32_bf16(wf[0], a0, acc, 0, 0, 0);
      acc = __builtin_amdgcn_mfma_f32_16x16x32_bf16(wf[1], a1, acc, 0, 0, 0);
      short* dst = (f0 < 512) ? Qs : Ks;
      svec4 pk;
#pragma unroll
      for (int g = 0; g < 4; ++g) pk[g] = f2bf(acc[g]);
      *(svec4*)(dst + (size_t)(r0 + ml) * 512 + (f0 & 511) + quad * 4) = pk;
    } else {
      // D[row][f] = X·W^T : lane holds 4 consecutive t -> svec4 into Vt
      acc = __builtin_amdgcn_mfma_f32_16x16x32_bf16(a0, wf[0], acc, 0, 0, 0);
      acc = __builtin_amdgcn_mfma_f32_16x16x32_bf16(a1, wf[1], acc, 0, 0, 0);
      int fl = f0 + ml - 1024;
      int hh = fl >> 6, dd = fl & 63;
      svec4 pk;
#pragma unroll
      for (int g = 0; g < 4; ++g) pk[g] = f2bf(acc[g]);
      *(svec4*)(Vt + ((((size_t)bq * 16 + nseg) * 8 + hh) * 64 + dd) * 512 +
                sbase) = pk;
    }
  };

  int base = fq * 24;
  bfrag wA[2], wB[2];
  loadW(wA, base);
#pragma unroll 1
  for (int it = 0; it < 12; ++it) {
    int nt0 = base + it * 2;
    loadW(wB, nt0 + 1);
    emit(wA, nt0);
    loadW(wA, (it < 11) ? nt0 + 2 : base);
    emit(wB, nt0 + 1);
  }
}

// ---------------- Kernel 3: segment attention, no-max softmax, S^T=K·Q^T ----
// 237-us build's schedule (nq=4, grid 512, (256,2), K+V dbuf) with the
// R4-verified transpose-free PV: the S^T C-layout (lane q=ml, t=quad*4+g)
// IS the B-operand layout of mfma_f32_16x16x16_bf16 (k=quad*4+j), so
// exp+pack feeds PV directly. Zero DS-pipe traffic, zero bank conflicts.
// Do NOT force >=4 waves/EU (R4: 128-reg cap -> scratch spill).
__global__ __launch_bounds__(256, 2) void attn_kernel(
    const short* __restrict__ Qs, const short* __restrict__ Ks,
    const short* __restrict__ Vt, const int* __restrict__ perm,
    short* __restrict__ aout) {
  int tid = threadIdx.x;
  int w = tid >> 6, lane = tid & 63;
  int ml = lane & 15, quad = lane >> 4;
  int sh = blockIdx.x & 255;
  int qq = blockIdx.x >> 8;
  int b = sh >> 7;
  int n = (sh >> 3) & 15;
  int h = sh & 7;
  size_t segrow = (size_t)(b * 8192 + n * 512);
  const short* Qseg = Qs + segrow * 512 + h * 64;
  const short* Kseg = Ks + segrow * 512 + h * 64;
  const short* Vseg = Vt + (((size_t)(b * 16 + n) * 8 + h) * 64) * 512;
  int q0 = qq * 256 + w * 64;  // 64 q-cols per wave (4 n-tiles)
  bfrag qa[4][2];
#pragma unroll
  for (int nq = 0; nq < 4; ++nq)
#pragma unroll
    for (int ks = 0; ks < 2; ++ks)
      qa[nq][ks] = *(const bfrag*)(Qseg + (size_t)(q0 + nq * 16 + ml) * 512 +
                                   ks * 32 + quad * 8);
  ffrag o[4][4];
  float lrun[4] = {0.f, 0.f, 0.f, 0.f};
#pragma unroll
  for (int nq = 0; nq < 4; ++nq)
#pragma unroll
    for (int dt = 0; dt < 4; ++dt) o[nq][dt] = (ffrag){0.f, 0.f, 0.f, 0.f};

  auto loadK = [&](bfrag (&kk)[2][2], int t0) {
#pragma unroll
    for (int mt = 0; mt < 2; ++mt)
#pragma unroll
      for (int ks = 0; ks < 2; ++ks)
        kk[mt][ks] = *(const bfrag*)(Kseg + (size_t)(t0 + mt * 16 + ml) * 512 +
                                     ks * 32 + quad * 8);
  };
  auto loadV = [&](bhalf4 (&vv)[4][2], int t0) {
#pragma unroll
    for (int dt = 0; dt < 4; ++dt)
#pragma unroll
      for (int hf = 0; hf < 2; ++hf)
        vv[dt][hf] = *(const bhalf4*)(Vseg + (size_t)(dt * 16 + ml) * 512 +
                                      t0 + hf * 16 + quad * 4);
  };
  auto body = [&](bfrag (&kk)[2][2], bhalf4 (&vv)[4][2]) {
#pragma unroll
    for (int nq = 0; nq < 4; ++nq) {
      ffrag c0 = {0.f, 0.f, 0.f, 0.f}, c1 = {0.f, 0.f, 0.f, 0.f};
      c0 = __builtin_amdgcn_mfma_f32_16x16x32_bf16(kk[0][0], qa[nq][0], c0, 0, 0, 0);
      c0 = __builtin_amdgcn_mfma_f32_16x16x32_bf16(kk[0][1], qa[nq][1], c0, 0, 0, 0);
      c1 = __builtin_amdgcn_mfma_f32_16x16x32_bf16(kk[1][0], qa[nq][0], c1, 0, 0, 0);
      c1 = __builtin_amdgcn_mfma_f32_16x16x32_bf16(kk[1][1], qa[nq][1], c1, 0, 0, 0);
      // P^T = 2^(S^T); lane holds q=ml, t = quad*4+g (c0), 16+quad*4+g (c1)
      float e0 = fexp2(c0[0]), e1 = fexp2(c0[1]);
      float e2 = fexp2(c0[2]), e3 = fexp2(c0[3]);
      float e4 = fexp2(c1[0]), e5 = fexp2(c1[1]);
      float e6 = fexp2(c1[2]), e7 = fexp2(c1[3]);
      lrun[nq] += ((e0 + e1) + (e2 + e3)) + ((e4 + e5) + (e6 + e7));
      uvec2 u0, u1;
      u0[0] = pk2f(e0, e1); u0[1] = pk2f(e2, e3);
      u1[0] = pk2f(e4, e5); u1[1] = pk2f(e6, e7);
      bhalf4 pb0 = __builtin_bit_cast(bhalf4, u0);  // B-frag t in [t0,t0+16)
      bhalf4 pb1 = __builtin_bit_cast(bhalf4, u1);  // B-frag t in [t0+16,+32)
      // O^T[d][q] += V^T · P^T via two K=16 MFMAs per dt
#pragma unroll
      for (int dt = 0; dt < 4; ++dt) {
        o[nq][dt] = __builtin_amdgcn_mfma_f32_16x16x16bf16_1k(
            vv[dt][0], pb0, o[nq][dt], 0, 0, 0);
        o[nq][dt] = __builtin_amdgcn_mfma_f32_16x16x16bf16_1k(
            vv[dt][1], pb1, o[nq][dt], 0, 0, 0);
      }
    }
  };

  bfrag kA[2][2], kB[2][2];
  bhalf4 vA[4][2], vB[4][2];
  loadK(kA, 0);
  loadV(vA, 0);
#pragma unroll 1
  for (int jj = 0; jj < 8; ++jj) {
    int t1 = jj * 64 + 32;
    loadK(kB, t1);
    loadV(vB, t1);
    body(kA, vA);
    int t2 = (jj * 64 + 64) & 511;  // wraps on last iter (unused)
    loadK(kA, t2);
    loadV(vA, t2);
    body(kB, vB);
  }
  // epilogue: reduce l across quads, normalize, perm-scatter
#pragma unroll
  for (int nq = 0; nq < 4; ++nq) {
    float l = lrun[nq];
    l += __shfl_xor(l, 16);
    l += __shfl_xor(l, 32);
    float inv = 1.f / l;
    int sout = q0 + nq * 16 + ml;
    int om = perm[n * 512 + sout];
    size_t base = ((size_t)(b * 8192 + om)) * 512 + h * 64;
#pragma unroll
    for (int dt = 0; dt < 4; ++dt) {
      svec4 pk;
#pragma unroll
      for (int g = 0; g < 4; ++g) pk[g] = f2bf(o[nq][dt][g] * inv);
      *(svec4*)(aout + base + dt * 16 + quad * 4) = pk;
    }
  }
}

// ---------------- Kernel 4: output projection (16384x512 @ 512x512^T) ------
// 237-us build: 128-row tiles, grid 512, (256,2). D[c][r] -> float4 stores.
__global__ __launch_bounds__(256, 2) void proj_kernel(
    const short* __restrict__ aout, const short* __restrict__ woutb,
    float* __restrict__ out) {
  int tid = threadIdx.x;
  int w = tid >> 6, lane = tid & 63;
  int ml = lane & 15, quad = lane >> 4;
  int rb = blockIdx.x >> 2;
  int cb = blockIdx.x & 3;
  int r0 = rb * 128 + w * 32;
  int c0 = cb * 128;
  ffrag acc[2][8];
#pragma unroll
  for (int mt = 0; mt < 2; ++mt)
#pragma unroll
    for (int nt = 0; nt < 8; ++nt) acc[mt][nt] = (ffrag){0.f, 0.f, 0.f, 0.f};

  auto loadA = [&](bfrag (&af)[2], int k0) {
#pragma unroll
    for (int mt = 0; mt < 2; ++mt)
      af[mt] = *(const bfrag*)(aout + (size_t)(r0 + mt * 16 + ml) * 512 + k0 +
                               quad * 8);
  };
  auto loadB = [&](bfrag (&bf)[8], int k0) {
#pragma unroll
    for (int nt = 0; nt < 8; ++nt)
      bf[nt] = *(const bfrag*)(woutb + (size_t)(c0 + nt * 16 + ml) * 512 + k0 +
                               quad * 8);
  };
  auto accum = [&](bfrag (&af)[2], bfrag (&bf)[8]) {
#pragma unroll
    for (int nt = 0; nt < 8; ++nt) {
      acc[0][nt] = __builtin_amdgcn_mfma_f32_16x16x32_bf16(bf[nt], af[0], acc[0][nt], 0, 0, 0);
      acc[1][nt] = __builtin_amdgcn_mfma_f32_16x16x32_bf16(bf[nt], af[1], acc[1][nt], 0, 0, 0);
    }
  };

  bfrag aA[2], aB[2], bA[8], bB[8];
  loadA(aA, 0);
  loadB(bA, 0);
#pragma unroll 1
  for (int it = 0; it < 8; ++it) {
    int k1 = it * 64 + 32;
    loadA(aB, k1);
    loadB(bB, k1);
    accum(aA, bA);
    int k2 = (it < 7) ? it * 64 + 64 : 0;
    loadA(aA, k2);
    loadB(bA, k2);
    accum(aB, bB);
  }
#pragma unroll
  for (int mt = 0; mt < 2; ++mt)
#pragma unroll
    for (int nt = 0; nt < 8; ++nt)
      *(ffrag*)(out + (size_t)(r0 + mt * 16 + ml) * 512 + c0 + nt * 16 +
                quad * 4) = acc[mt][nt];
}

extern "C" void kernel_launch(void* const* d_in, const int* in_sizes, int n_in,
                              void* d_out, int out_size, void* d_ws,
                              size_t ws_size, hipStream_t stream) {
  const float* q = (const float*)d_in[0];
  const float* w_qkv = (const float*)d_in[3];
  const float* w_out = (const float*)d_in[4];
  float* out = (float*)d_out;

  char* ws = (char*)d_ws;
  int* perm = (int*)ws;                       //     32768 B
  short* xmean = (short*)(ws + 32768);        //   2097152 B
  short* weff = (short*)(ws + 2129920);       //    196608 B
  short* woutb = (short*)(ws + 2326528);      //    524288 B
  short* Qs = (short*)(ws + 2850816);         //  16777216 B
  short* Ks = (short*)(ws + 19628032);        //  16777216 B
  short* Vt = (short*)(ws + 36405248);        //  16777216 B
  short* aout = (short*)(ws + 53182464);      //  16777216 B  (total ~70 MB)

  prep_kernel<<<5536, 256, 0, stream>>>(q, w_qkv, w_out, xmean, weff, woutb,
                                        perm);
  qkv_kernel<<<1024, 256, 0, stream>>>(xmean, weff, perm, Qs, Ks, Vt);
  attn_kernel<<<512, 256, 0, stream>>>(Qs, Ks, Vt, perm, aout);
  proj_kernel<<<512, 256, 0, stream>>>(aout, woutb, out);
}